// Round 2
// baseline (481.836 us; speedup 1.0000x reference)
//
#include <hip/hip_runtime.h>

// FrequencyDecomposition: blocked 8x8 DCT -> zigzag band masking -> blocked
// second transform (the reference einsum applies D . W . D^T again, NOT
// D^T W D -- we replicate the einsum exactly).
//
// x: [32, 3, 512, 512] fp32 -> out: [3, 32, 3, 512, 512] fp32
//
// v3b: even/odd-folded fast 8-point DCT everywhere (36 ops vs 64 per 8-pt
// transform; ~1950 VALU ops/thread vs ~2816 in v2, mostly literal-free
// v_add -> ~2x smaller code, relieves L1I). __launch_bounds__(256,4) caps
// VGPR at 128 for 4 waves/SIMD (was 3). Output is write-once (302 MB) ->
// nontemporal stores via native ext_vector_type (HIP float4 class is
// rejected by __builtin_nontemporal_store -- v3's compile failure).
//
// NOTE: ~190us of the measured dur_us is the harness's output re-poison
// fillBuffer (1.2 GB @ 78% HBM peak) -- not addressable from here.

namespace {

typedef float f32x4 __attribute__((ext_vector_type(4)));

// DCT-II orthonormal 8x8 matrix (rows k, cols i).
constexpr float DM[8][8] = {
  { 0.35355339059327373f, 0.35355339059327373f, 0.35355339059327373f, 0.35355339059327373f,
    0.35355339059327373f, 0.35355339059327373f, 0.35355339059327373f, 0.35355339059327373f },
  { 0.49039264020161522f, 0.41573480615127262f, 0.27778511650980114f, 0.09754516100806417f,
   -0.09754516100806417f,-0.27778511650980114f,-0.41573480615127262f,-0.49039264020161522f },
  { 0.46193976625564337f, 0.19134171618254492f,-0.19134171618254492f,-0.46193976625564337f,
   -0.46193976625564337f,-0.19134171618254492f, 0.19134171618254492f, 0.46193976625564337f },
  { 0.41573480615127262f,-0.09754516100806417f,-0.49039264020161522f,-0.27778511650980114f,
    0.27778511650980114f, 0.49039264020161522f, 0.09754516100806417f,-0.41573480615127262f },
  { 0.35355339059327373f,-0.35355339059327373f,-0.35355339059327373f, 0.35355339059327373f,
    0.35355339059327373f,-0.35355339059327373f,-0.35355339059327373f, 0.35355339059327373f },
  { 0.27778511650980114f,-0.49039264020161522f, 0.09754516100806417f, 0.41573480615127262f,
   -0.41573480615127262f,-0.09754516100806417f, 0.49039264020161522f,-0.27778511650980114f },
  { 0.19134171618254492f,-0.46193976625564337f, 0.46193976625564337f,-0.19134171618254492f,
   -0.19134171618254492f, 0.46193976625564337f,-0.46193976625564337f, 0.19134171618254492f },
  { 0.09754516100806417f,-0.27778511650980114f, 0.41573480615127262f,-0.49039264020161522f,
    0.49039264020161522f,-0.41573480615127262f, 0.27778511650980114f,-0.09754516100806417f }
};

// Standard JPEG zigzag index of (k,l) -- matches reference _zigzag_indices.
constexpr int ZZ[8][8] = {
  { 0,  1,  5,  6, 14, 15, 27, 28},
  { 2,  4,  7, 13, 16, 26, 29, 42},
  { 3,  8, 12, 17, 25, 30, 41, 43},
  { 9, 11, 18, 24, 31, 40, 44, 53},
  {10, 19, 23, 32, 39, 45, 52, 54},
  {20, 22, 33, 38, 46, 51, 55, 60},
  {21, 34, 37, 47, 50, 56, 59, 61},
  {35, 36, 48, 49, 57, 58, 62, 63}
};

// band 0 = low (z < 16), band 2 = high (z >= 48), band 1 = mid.
constexpr int band_of(int k, int l) {
  return ZZ[k][l] < 16 ? 0 : (ZZ[k][l] >= 48 ? 2 : 1);
}

// Fast-DCT constants.
constexpr float R8 = 0.35355339059327373f;  // 1/sqrt(8)
constexpr float A8 = 0.46193976625564337f;  // DM[2][0]
constexpr float B8 = 0.19134171618254492f;  // DM[2][1]
constexpr float C1 = 0.49039264020161522f;  // DM[1][0]
constexpr float C3 = 0.41573480615127262f;  // DM[1][1]
constexpr float C5 = 0.27778511650980114f;  // DM[1][2]
constexpr float C7 = 0.09754516100806417f;  // DM[1][3]

// z[c] = sum_j w[j] * DM[c][j], given the even/odd folds of w:
//   e_j = w[j] + w[7-j], o_j = w[j] - w[7-j]  (j = 0..3).
// Even rows of DM are symmetric in j, odd rows antisymmetric.
__device__ __forceinline__ void dct8_eo(float e0, float e1, float e2, float e3,
                                        float o0, float o1, float o2, float o3,
                                        float y[8]) {
  const float s03 = e0 + e3, s12 = e1 + e2;
  const float d03 = e0 - e3, d12 = e1 - e2;
  y[0] = R8 * (s03 + s12);
  y[4] = R8 * (s03 - s12);
  y[2] = fmaf( B8, d12, A8 * d03);
  y[6] = fmaf(-A8, d12, B8 * d03);
  y[1] = fmaf( C7, o3, fmaf( C5, o2, fmaf( C3, o1, C1 * o0)));
  y[3] = fmaf(-C5, o3, fmaf(-C1, o2, fmaf(-C7, o1, C3 * o0)));
  y[5] = fmaf( C3, o3, fmaf( C7, o2, fmaf(-C1, o1, C5 * o0)));
  y[7] = fmaf(-C1, o3, fmaf( C3, o2, fmaf(-C5, o1, C7 * o0)));
}

__device__ __forceinline__ void dct8(float x0, float x1, float x2, float x3,
                                     float x4, float x5, float x6, float x7,
                                     float y[8]) {
  dct8_eo(x0 + x7, x1 + x6, x2 + x5, x3 + x4,
          x0 - x7, x1 - x6, x2 - x5, x3 - x4, y);
}

__device__ __forceinline__ void store_nt8(float* p, const float y[8]) {
  f32x4 lo = { y[0], y[1], y[2], y[3] };
  f32x4 hi = { y[4], y[5], y[6], y[7] };
  __builtin_nontemporal_store(lo, (f32x4*)p);
  __builtin_nontemporal_store(hi, (f32x4*)(p + 4));
}

} // namespace

// x: [B=32, C=3, H=512, W=512]; 96 images of 512x512; 64x64 blocks per image.
__global__ __launch_bounds__(256, 4) void freq_decomp_kernel(
    const float* __restrict__ x, float* __restrict__ out) {
  const int tid = blockIdx.x * 256 + threadIdx.x;   // 0 .. 393215, exact grid
  const int wb = tid & 63;          // block col
  const int hb = (tid >> 6) & 63;   // block row
  const int bc = tid >> 12;         // image index 0..95

  const size_t base = ((size_t)bc << 18) + (size_t)hb * 4096 + (size_t)(wb * 8);
  const float* in = x + base;

  // ---- phase 1: row transform, folded: V[r][c] = sum_j x[r][j] DM[c][j] ----
  float V[8][8];
#pragma unroll
  for (int r = 0; r < 8; ++r) {
    const float4 a = *(const float4*)(in + (size_t)r * 512);
    const float4 b = *(const float4*)(in + (size_t)r * 512 + 4);
    dct8(a.x, a.y, a.z, a.w, b.x, b.y, b.z, b.w, V[r]);
  }

  // ---- phase 2: column transform: T[k][l] = sum_i DM[k][i] V[i][l] ----
  float T[8][8];
#pragma unroll
  for (int l = 0; l < 8; ++l) {
    float col[8];
    dct8(V[0][l], V[1][l], V[2][l], V[3][l],
         V[4][l], V[5][l], V[6][l], V[7][l], col);
#pragma unroll
    for (int k = 0; k < 8; ++k) T[k][l] = col[k];
  }

  // ---- phase 3: per output row i, all three bands ----
  // A_n[l] = sum_k [band(k,l)==n] DM[i][k] T[k][l]  (bands partition (k,l),
  // so the 64 fmas split across the three accumulators with no waste).
  // y_n[j] = sum_l A_n[l] DM[j][l] -- again an 8-pt DCT in l, folded.
  // Low band: only cols 0..5 nonzero (AL[6]=AL[7]=0); high: cols 2..7.
  float* const olow  = out + base;                   // band stride 96*512*512
  float* const omid  = olow + 25165824;
  float* const ohigh = omid + 25165824;

#pragma unroll
  for (int i = 0; i < 8; ++i) {
    float AL[8], AM[8], AH[8];
#pragma unroll
    for (int l = 0; l < 8; ++l) {
      float sl = 0.0f, sm = 0.0f, sh = 0.0f;
#pragma unroll
      for (int k = 0; k < 8; ++k) {
        const int b = band_of(k, l);
        if (b == 0) sl = fmaf(DM[i][k], T[k][l], sl);
        else if (b == 1) sm = fmaf(DM[i][k], T[k][l], sm);
        else sh = fmaf(DM[i][k], T[k][l], sh);
      }
      AL[l] = sl; AM[l] = sm; AH[l] = sh;
    }

    float yl[8], ym[8], yh[8];
    // low: e = {AL0, AL1, AL2+AL5, AL3+AL4}, o = {AL0, AL1, AL2-AL5, AL3-AL4}
    dct8_eo(AL[0], AL[1], AL[2] + AL[5], AL[3] + AL[4],
            AL[0], AL[1], AL[2] - AL[5], AL[3] - AL[4], yl);
    // mid: full fold
    dct8(AM[0], AM[1], AM[2], AM[3], AM[4], AM[5], AM[6], AM[7], ym);
    // high: e = {AH7, AH6, AH2+AH5, AH3+AH4}, o = {-AH7, -AH6, AH2-AH5, AH3-AH4}
    dct8_eo( AH[7],  AH[6], AH[2] + AH[5], AH[3] + AH[4],
            -AH[7], -AH[6], AH[2] - AH[5], AH[3] - AH[4], yh);

    const size_t roff = (size_t)i * 512;
    store_nt8(olow  + roff, yl);
    store_nt8(omid  + roff, ym);
    store_nt8(ohigh + roff, yh);
  }
}

extern "C" void kernel_launch(void* const* d_in, const int* in_sizes, int n_in,
                              void* d_out, int out_size, void* d_ws, size_t ws_size,
                              hipStream_t stream) {
  (void)in_sizes; (void)n_in; (void)d_ws; (void)ws_size; (void)out_size;
  const float* x = (const float*)d_in[0];
  float* out = (float*)d_out;
  // 32*3 images * 64*64 blocks = 393216 threads = 1536 blocks of 256.
  freq_decomp_kernel<<<1536, 256, 0, stream>>>(x, out);
}

// Round 3
// 382.933 us; speedup vs baseline: 1.2583x; 1.2583x over previous
//
#include <hip/hip_runtime.h>

// FrequencyDecomposition: blocked 8x8 DCT -> zigzag band masking -> blocked
// second transform (the reference einsum applies D . W . D^T again, NOT
// D^T W D -- we replicate the einsum exactly).
//
// x: [32, 3, 512, 512] fp32 -> out: [3, 32, 3, 512, 512] fp32
//
// v4: folded fast 8-pt DCT (v3b) + REGULAR float4 stores. v3b's
// __builtin_nontemporal_store caused 1.77x write amplification
// (WRITE_SIZE 534 MB vs 302 MB ideal): the nt/evict-first bit defeats L2
// write-combining, so sub-line sectors stream to HBM -> store-drain
// stalls (VALUBusy 8.5%, HBM eff. 2.7 TB/s, kernel 220 us). Plain
// coalesced dwordx4 stores merge to full 64B lines in L2 before drain.
//
// NOTE: ~190us of the measured dur_us is the harness's output re-poison
// fillBuffer (1.2 GB @ 78% HBM peak) -- not addressable from here.

namespace {

// DCT-II orthonormal 8x8 matrix (rows k, cols i).
constexpr float DM[8][8] = {
  { 0.35355339059327373f, 0.35355339059327373f, 0.35355339059327373f, 0.35355339059327373f,
    0.35355339059327373f, 0.35355339059327373f, 0.35355339059327373f, 0.35355339059327373f },
  { 0.49039264020161522f, 0.41573480615127262f, 0.27778511650980114f, 0.09754516100806417f,
   -0.09754516100806417f,-0.27778511650980114f,-0.41573480615127262f,-0.49039264020161522f },
  { 0.46193976625564337f, 0.19134171618254492f,-0.19134171618254492f,-0.46193976625564337f,
   -0.46193976625564337f,-0.19134171618254492f, 0.19134171618254492f, 0.46193976625564337f },
  { 0.41573480615127262f,-0.09754516100806417f,-0.49039264020161522f,-0.27778511650980114f,
    0.27778511650980114f, 0.49039264020161522f, 0.09754516100806417f,-0.41573480615127262f },
  { 0.35355339059327373f,-0.35355339059327373f,-0.35355339059327373f, 0.35355339059327373f,
    0.35355339059327373f,-0.35355339059327373f,-0.35355339059327373f, 0.35355339059327373f },
  { 0.27778511650980114f,-0.49039264020161522f, 0.09754516100806417f, 0.41573480615127262f,
   -0.41573480615127262f,-0.09754516100806417f, 0.49039264020161522f,-0.27778511650980114f },
  { 0.19134171618254492f,-0.46193976625564337f, 0.46193976625564337f,-0.19134171618254492f,
   -0.19134171618254492f, 0.46193976625564337f,-0.46193976625564337f, 0.19134171618254492f },
  { 0.09754516100806417f,-0.27778511650980114f, 0.41573480615127262f,-0.49039264020161522f,
    0.49039264020161522f,-0.41573480615127262f, 0.27778511650980114f,-0.09754516100806417f }
};

// Standard JPEG zigzag index of (k,l) -- matches reference _zigzag_indices.
constexpr int ZZ[8][8] = {
  { 0,  1,  5,  6, 14, 15, 27, 28},
  { 2,  4,  7, 13, 16, 26, 29, 42},
  { 3,  8, 12, 17, 25, 30, 41, 43},
  { 9, 11, 18, 24, 31, 40, 44, 53},
  {10, 19, 23, 32, 39, 45, 52, 54},
  {20, 22, 33, 38, 46, 51, 55, 60},
  {21, 34, 37, 47, 50, 56, 59, 61},
  {35, 36, 48, 49, 57, 58, 62, 63}
};

// band 0 = low (z < 16), band 2 = high (z >= 48), band 1 = mid.
constexpr int band_of(int k, int l) {
  return ZZ[k][l] < 16 ? 0 : (ZZ[k][l] >= 48 ? 2 : 1);
}

// Fast-DCT constants.
constexpr float R8 = 0.35355339059327373f;  // 1/sqrt(8)
constexpr float A8 = 0.46193976625564337f;  // DM[2][0]
constexpr float B8 = 0.19134171618254492f;  // DM[2][1]
constexpr float C1 = 0.49039264020161522f;  // DM[1][0]
constexpr float C3 = 0.41573480615127262f;  // DM[1][1]
constexpr float C5 = 0.27778511650980114f;  // DM[1][2]
constexpr float C7 = 0.09754516100806417f;  // DM[1][3]

// z[c] = sum_j w[j] * DM[c][j], given the even/odd folds of w:
//   e_j = w[j] + w[7-j], o_j = w[j] - w[7-j]  (j = 0..3).
// Even rows of DM are symmetric in j, odd rows antisymmetric.
__device__ __forceinline__ void dct8_eo(float e0, float e1, float e2, float e3,
                                        float o0, float o1, float o2, float o3,
                                        float y[8]) {
  const float s03 = e0 + e3, s12 = e1 + e2;
  const float d03 = e0 - e3, d12 = e1 - e2;
  y[0] = R8 * (s03 + s12);
  y[4] = R8 * (s03 - s12);
  y[2] = fmaf( B8, d12, A8 * d03);
  y[6] = fmaf(-A8, d12, B8 * d03);
  y[1] = fmaf( C7, o3, fmaf( C5, o2, fmaf( C3, o1, C1 * o0)));
  y[3] = fmaf(-C5, o3, fmaf(-C1, o2, fmaf(-C7, o1, C3 * o0)));
  y[5] = fmaf( C3, o3, fmaf( C7, o2, fmaf(-C1, o1, C5 * o0)));
  y[7] = fmaf(-C1, o3, fmaf( C3, o2, fmaf(-C5, o1, C7 * o0)));
}

__device__ __forceinline__ void dct8(float x0, float x1, float x2, float x3,
                                     float x4, float x5, float x6, float x7,
                                     float y[8]) {
  dct8_eo(x0 + x7, x1 + x6, x2 + x5, x3 + x4,
          x0 - x7, x1 - x6, x2 - x5, x3 - x4, y);
}

__device__ __forceinline__ void store8(float* p, const float y[8]) {
  *(float4*)p       = make_float4(y[0], y[1], y[2], y[3]);
  *(float4*)(p + 4) = make_float4(y[4], y[5], y[6], y[7]);
}

} // namespace

// x: [B=32, C=3, H=512, W=512]; 96 images of 512x512; 64x64 blocks per image.
__global__ __launch_bounds__(256, 4) void freq_decomp_kernel(
    const float* __restrict__ x, float* __restrict__ out) {
  const int tid = blockIdx.x * 256 + threadIdx.x;   // 0 .. 393215, exact grid
  const int wb = tid & 63;          // block col
  const int hb = (tid >> 6) & 63;   // block row
  const int bc = tid >> 12;         // image index 0..95

  const size_t base = ((size_t)bc << 18) + (size_t)hb * 4096 + (size_t)(wb * 8);
  const float* in = x + base;

  // ---- phase 1: row transform, folded: V[r][c] = sum_j x[r][j] DM[c][j] ----
  float V[8][8];
#pragma unroll
  for (int r = 0; r < 8; ++r) {
    const float4 a = *(const float4*)(in + (size_t)r * 512);
    const float4 b = *(const float4*)(in + (size_t)r * 512 + 4);
    dct8(a.x, a.y, a.z, a.w, b.x, b.y, b.z, b.w, V[r]);
  }

  // ---- phase 2: column transform: T[k][l] = sum_i DM[k][i] V[i][l] ----
  float T[8][8];
#pragma unroll
  for (int l = 0; l < 8; ++l) {
    float col[8];
    dct8(V[0][l], V[1][l], V[2][l], V[3][l],
         V[4][l], V[5][l], V[6][l], V[7][l], col);
#pragma unroll
    for (int k = 0; k < 8; ++k) T[k][l] = col[k];
  }

  // ---- phase 3: per output row i, all three bands ----
  // A_n[l] = sum_k [band(k,l)==n] DM[i][k] T[k][l]  (bands partition (k,l),
  // so the 64 fmas split across the three accumulators with no waste).
  // y_n[j] = sum_l A_n[l] DM[j][l] -- again an 8-pt DCT in l, folded.
  // Low band: only cols 0..5 nonzero (AL[6]=AL[7]=0); high: cols 2..7.
  float* const olow  = out + base;                   // band stride 96*512*512
  float* const omid  = olow + 25165824;
  float* const ohigh = omid + 25165824;

#pragma unroll
  for (int i = 0; i < 8; ++i) {
    float AL[8], AM[8], AH[8];
#pragma unroll
    for (int l = 0; l < 8; ++l) {
      float sl = 0.0f, sm = 0.0f, sh = 0.0f;
#pragma unroll
      for (int k = 0; k < 8; ++k) {
        const int b = band_of(k, l);
        if (b == 0) sl = fmaf(DM[i][k], T[k][l], sl);
        else if (b == 1) sm = fmaf(DM[i][k], T[k][l], sm);
        else sh = fmaf(DM[i][k], T[k][l], sh);
      }
      AL[l] = sl; AM[l] = sm; AH[l] = sh;
    }

    float yl[8], ym[8], yh[8];
    // low: e = {AL0, AL1, AL2+AL5, AL3+AL4}, o = {AL0, AL1, AL2-AL5, AL3-AL4}
    dct8_eo(AL[0], AL[1], AL[2] + AL[5], AL[3] + AL[4],
            AL[0], AL[1], AL[2] - AL[5], AL[3] - AL[4], yl);
    // mid: full fold
    dct8(AM[0], AM[1], AM[2], AM[3], AM[4], AM[5], AM[6], AM[7], ym);
    // high: e = {AH7, AH6, AH2+AH5, AH3+AH4}, o = {-AH7, -AH6, AH2-AH5, AH3-AH4}
    dct8_eo( AH[7],  AH[6], AH[2] + AH[5], AH[3] + AH[4],
            -AH[7], -AH[6], AH[2] - AH[5], AH[3] - AH[4], yh);

    const size_t roff = (size_t)i * 512;
    store8(olow  + roff, yl);
    store8(omid  + roff, ym);
    store8(ohigh + roff, yh);
  }
}

extern "C" void kernel_launch(void* const* d_in, const int* in_sizes, int n_in,
                              void* d_out, int out_size, void* d_ws, size_t ws_size,
                              hipStream_t stream) {
  (void)in_sizes; (void)n_in; (void)d_ws; (void)ws_size; (void)out_size;
  const float* x = (const float*)d_in[0];
  float* out = (float*)d_out;
  // 32*3 images * 64*64 blocks = 393216 threads = 1536 blocks of 256.
  freq_decomp_kernel<<<1536, 256, 0, stream>>>(x, out);
}

// Round 4
// 377.113 us; speedup vs baseline: 1.2777x; 1.0154x over previous
//
#include <hip/hip_runtime.h>

// FrequencyDecomposition: blocked 8x8 DCT -> zigzag band masking -> blocked
// second transform (the reference einsum applies D . W . D^T again, NOT
// D^T W D -- we replicate the einsum exactly).
//
// x: [32, 3, 512, 512] fp32 -> out: [3, 32, 3, 512, 512] fp32
//
// v5: folded fast 8-pt DCT (kept from v4) + EXPLICIT full-block prefetch +
// __launch_bounds__(256,3).
//   - v4's (256,4) made the scheduler target 64 VGPR (8 waves/SIMD), but the
//     grid only supplies 6 waves/SIMD -- phantom occupancy. At 64 VGPR the
//     scheduler sank each row's loads to right before use: 8 serialized
//     ~500cy load round-trips/thread, latency-bound (VALUBusy 8.5%,
//     HBM ~2 TB/s).
//   - Now: all 16 global_load_dwordx4 issued back-to-back into a live X
//     array (16 outstanding loads/wave, ~48/SIMD at 3 waves), latency paid
//     once. VGPR cap 170 gives the scheduler room (peak live ~150).
//
// NOTE: ~190us of the measured dur_us is the harness's output re-poison
// fillBuffer (1.2 GB @ 78% HBM peak) -- not addressable from here.

namespace {

// DCT-II orthonormal 8x8 matrix (rows k, cols i).
constexpr float DM[8][8] = {
  { 0.35355339059327373f, 0.35355339059327373f, 0.35355339059327373f, 0.35355339059327373f,
    0.35355339059327373f, 0.35355339059327373f, 0.35355339059327373f, 0.35355339059327373f },
  { 0.49039264020161522f, 0.41573480615127262f, 0.27778511650980114f, 0.09754516100806417f,
   -0.09754516100806417f,-0.27778511650980114f,-0.41573480615127262f,-0.49039264020161522f },
  { 0.46193976625564337f, 0.19134171618254492f,-0.19134171618254492f,-0.46193976625564337f,
   -0.46193976625564337f,-0.19134171618254492f, 0.19134171618254492f, 0.46193976625564337f },
  { 0.41573480615127262f,-0.09754516100806417f,-0.49039264020161522f,-0.27778511650980114f,
    0.27778511650980114f, 0.49039264020161522f, 0.09754516100806417f,-0.41573480615127262f },
  { 0.35355339059327373f,-0.35355339059327373f,-0.35355339059327373f, 0.35355339059327373f,
    0.35355339059327373f,-0.35355339059327373f,-0.35355339059327373f, 0.35355339059327373f },
  { 0.27778511650980114f,-0.49039264020161522f, 0.09754516100806417f, 0.41573480615127262f,
   -0.41573480615127262f,-0.09754516100806417f, 0.49039264020161522f,-0.27778511650980114f },
  { 0.19134171618254492f,-0.46193976625564337f, 0.46193976625564337f,-0.19134171618254492f,
   -0.19134171618254492f, 0.46193976625564337f,-0.46193976625564337f, 0.19134171618254492f },
  { 0.09754516100806417f,-0.27778511650980114f, 0.41573480615127262f,-0.49039264020161522f,
    0.49039264020161522f,-0.41573480615127262f, 0.27778511650980114f,-0.09754516100806417f }
};

// Standard JPEG zigzag index of (k,l) -- matches reference _zigzag_indices.
constexpr int ZZ[8][8] = {
  { 0,  1,  5,  6, 14, 15, 27, 28},
  { 2,  4,  7, 13, 16, 26, 29, 42},
  { 3,  8, 12, 17, 25, 30, 41, 43},
  { 9, 11, 18, 24, 31, 40, 44, 53},
  {10, 19, 23, 32, 39, 45, 52, 54},
  {20, 22, 33, 38, 46, 51, 55, 60},
  {21, 34, 37, 47, 50, 56, 59, 61},
  {35, 36, 48, 49, 57, 58, 62, 63}
};

// band 0 = low (z < 16), band 2 = high (z >= 48), band 1 = mid.
constexpr int band_of(int k, int l) {
  return ZZ[k][l] < 16 ? 0 : (ZZ[k][l] >= 48 ? 2 : 1);
}

// Fast-DCT constants.
constexpr float R8 = 0.35355339059327373f;  // 1/sqrt(8)
constexpr float A8 = 0.46193976625564337f;  // DM[2][0]
constexpr float B8 = 0.19134171618254492f;  // DM[2][1]
constexpr float C1 = 0.49039264020161522f;  // DM[1][0]
constexpr float C3 = 0.41573480615127262f;  // DM[1][1]
constexpr float C5 = 0.27778511650980114f;  // DM[1][2]
constexpr float C7 = 0.09754516100806417f;  // DM[1][3]

// z[c] = sum_j w[j] * DM[c][j], given the even/odd folds of w:
//   e_j = w[j] + w[7-j], o_j = w[j] - w[7-j]  (j = 0..3).
// Even rows of DM are symmetric in j, odd rows antisymmetric.
__device__ __forceinline__ void dct8_eo(float e0, float e1, float e2, float e3,
                                        float o0, float o1, float o2, float o3,
                                        float y[8]) {
  const float s03 = e0 + e3, s12 = e1 + e2;
  const float d03 = e0 - e3, d12 = e1 - e2;
  y[0] = R8 * (s03 + s12);
  y[4] = R8 * (s03 - s12);
  y[2] = fmaf( B8, d12, A8 * d03);
  y[6] = fmaf(-A8, d12, B8 * d03);
  y[1] = fmaf( C7, o3, fmaf( C5, o2, fmaf( C3, o1, C1 * o0)));
  y[3] = fmaf(-C5, o3, fmaf(-C1, o2, fmaf(-C7, o1, C3 * o0)));
  y[5] = fmaf( C3, o3, fmaf( C7, o2, fmaf(-C1, o1, C5 * o0)));
  y[7] = fmaf(-C1, o3, fmaf( C3, o2, fmaf(-C5, o1, C7 * o0)));
}

__device__ __forceinline__ void dct8(float x0, float x1, float x2, float x3,
                                     float x4, float x5, float x6, float x7,
                                     float y[8]) {
  dct8_eo(x0 + x7, x1 + x6, x2 + x5, x3 + x4,
          x0 - x7, x1 - x6, x2 - x5, x3 - x4, y);
}

__device__ __forceinline__ void store8(float* p, const float y[8]) {
  *(float4*)p       = make_float4(y[0], y[1], y[2], y[3]);
  *(float4*)(p + 4) = make_float4(y[4], y[5], y[6], y[7]);
}

} // namespace

// x: [B=32, C=3, H=512, W=512]; 96 images of 512x512; 64x64 blocks per image.
__global__ __launch_bounds__(256, 3) void freq_decomp_kernel(
    const float* __restrict__ x, float* __restrict__ out) {
  const int tid = blockIdx.x * 256 + threadIdx.x;   // 0 .. 393215, exact grid
  const int wb = tid & 63;          // block col
  const int hb = (tid >> 6) & 63;   // block row
  const int bc = tid >> 12;         // image index 0..95

  const size_t base = ((size_t)bc << 18) + (size_t)hb * 4096 + (size_t)(wb * 8);
  const float* in = x + base;

  // ---- phase 0: issue ALL 16 loads back-to-back (16 outstanding/wave) ----
  float4 xa[8], xb[8];
#pragma unroll
  for (int r = 0; r < 8; ++r) {
    xa[r] = *(const float4*)(in + (size_t)r * 512);
    xb[r] = *(const float4*)(in + (size_t)r * 512 + 4);
  }

  // ---- phase 1: row transform, folded: V[r][c] = sum_j x[r][j] DM[c][j] ----
  float V[8][8];
#pragma unroll
  for (int r = 0; r < 8; ++r) {
    dct8(xa[r].x, xa[r].y, xa[r].z, xa[r].w,
         xb[r].x, xb[r].y, xb[r].z, xb[r].w, V[r]);
  }

  // ---- phase 2: column transform: T[k][l] = sum_i DM[k][i] V[i][l] ----
  float T[8][8];
#pragma unroll
  for (int l = 0; l < 8; ++l) {
    float col[8];
    dct8(V[0][l], V[1][l], V[2][l], V[3][l],
         V[4][l], V[5][l], V[6][l], V[7][l], col);
#pragma unroll
    for (int k = 0; k < 8; ++k) T[k][l] = col[k];
  }

  // ---- phase 3: per output row i, all three bands ----
  // A_n[l] = sum_k [band(k,l)==n] DM[i][k] T[k][l]  (bands partition (k,l),
  // so the 64 fmas split across the three accumulators with no waste).
  // y_n[j] = sum_l A_n[l] DM[j][l] -- again an 8-pt DCT in l, folded.
  // Low band: only cols 0..5 nonzero (AL[6]=AL[7]=0); high: cols 2..7.
  float* const olow  = out + base;                   // band stride 96*512*512
  float* const omid  = olow + 25165824;
  float* const ohigh = omid + 25165824;

#pragma unroll
  for (int i = 0; i < 8; ++i) {
    float AL[8], AM[8], AH[8];
#pragma unroll
    for (int l = 0; l < 8; ++l) {
      float sl = 0.0f, sm = 0.0f, sh = 0.0f;
#pragma unroll
      for (int k = 0; k < 8; ++k) {
        const int b = band_of(k, l);
        if (b == 0) sl = fmaf(DM[i][k], T[k][l], sl);
        else if (b == 1) sm = fmaf(DM[i][k], T[k][l], sm);
        else sh = fmaf(DM[i][k], T[k][l], sh);
      }
      AL[l] = sl; AM[l] = sm; AH[l] = sh;
    }

    float yl[8], ym[8], yh[8];
    // low: e = {AL0, AL1, AL2+AL5, AL3+AL4}, o = {AL0, AL1, AL2-AL5, AL3-AL4}
    dct8_eo(AL[0], AL[1], AL[2] + AL[5], AL[3] + AL[4],
            AL[0], AL[1], AL[2] - AL[5], AL[3] - AL[4], yl);
    // mid: full fold
    dct8(AM[0], AM[1], AM[2], AM[3], AM[4], AM[5], AM[6], AM[7], ym);
    // high: e = {AH7, AH6, AH2+AH5, AH3+AH4}, o = {-AH7, -AH6, AH2-AH5, AH3-AH4}
    dct8_eo( AH[7],  AH[6], AH[2] + AH[5], AH[3] + AH[4],
            -AH[7], -AH[6], AH[2] - AH[5], AH[3] - AH[4], yh);

    const size_t roff = (size_t)i * 512;
    store8(olow  + roff, yl);
    store8(omid  + roff, ym);
    store8(ohigh + roff, yh);
  }
}

extern "C" void kernel_launch(void* const* d_in, const int* in_sizes, int n_in,
                              void* d_out, int out_size, void* d_ws, size_t ws_size,
                              hipStream_t stream) {
  (void)in_sizes; (void)n_in; (void)d_ws; (void)ws_size; (void)out_size;
  const float* x = (const float*)d_in[0];
  float* out = (float*)d_out;
  // 32*3 images * 64*64 blocks = 393216 threads = 1536 blocks of 256.
  freq_decomp_kernel<<<1536, 256, 0, stream>>>(x, out);
}